// Round 4
// baseline (284.099 us; speedup 1.0000x reference)
//
#include <hip/hip_runtime.h>
#include <stdint.h>
#include <stddef.h>

#define M_DIM 2048
#define N_DIM 11008
#define K_DIM 4096
#define BM 128
#define BN 256
#define BK 64
#define NT (K_DIM / BK)   // 64
#define NBM (M_DIM / BM)  // 16
#define NBN (N_DIM / BN)  // 43
#define GRID (NBM * NBN)  // 688 (divisible by 8 -> XCD swizzle bijective)

typedef __attribute__((ext_vector_type(4))) float f32x4;
typedef __attribute__((ext_vector_type(4))) float f4;
typedef __attribute__((ext_vector_type(4))) int i4;
typedef __attribute__((ext_vector_type(8))) __bf16 bf16x8;
typedef __attribute__((ext_vector_type(8))) unsigned short us8;

#define VMCNT2() asm volatile("s_waitcnt vmcnt(2)" ::: "memory")
#define VMCNT0() asm volatile("s_waitcnt vmcnt(0)" ::: "memory")
#define FENCE() asm volatile("" ::: "memory")
#define BARRIER()                 \
  do {                            \
    FENCE();                      \
    __builtin_amdgcn_s_barrier(); \
    FENCE();                      \
  } while (0)

// round-to-nearest-even fp32 -> bf16
__device__ inline unsigned short f2bf(float f) {
  unsigned u = __builtin_bit_cast(unsigned, f);
  u += 0x7fffu + ((u >> 16) & 1u);
  return (unsigned short)(u >> 16);
}

__device__ inline void gload_lds16(const void* g, void* l) {
  __builtin_amdgcn_global_load_lds((const __attribute__((address_space(1))) void*)g,
                                   (__attribute__((address_space(3))) void*)l, 16, 0, 0);
}

// ---------------- conversion kernels ----------------

__global__ void __launch_bounds__(256) cvt_x_kernel(const float* __restrict__ x,
                                                    us8* __restrict__ xb, int n8) {
  int i = blockIdx.x * 256 + threadIdx.x;
  if (i >= n8) return;
  const f4* src = (const f4*)x;
  f4 a = src[2 * i];
  f4 b = src[2 * i + 1];
  us8 o;
  o[0] = f2bf(a[0]); o[1] = f2bf(a[1]); o[2] = f2bf(a[2]); o[3] = f2bf(a[3]);
  o[4] = f2bf(b[0]); o[5] = f2bf(b[1]); o[6] = f2bf(b[2]); o[7] = f2bf(b[3]);
  xb[i] = o;
}

// W_q arrives as int32 per element; int8-range values are exact in bf16.
__global__ void __launch_bounds__(256) cvt_w_kernel(const int* __restrict__ w,
                                                    us8* __restrict__ wb, int n16) {
  int i = blockIdx.x * 256 + threadIdx.x;
  if (i >= n16) return;
  const i4* src = (const i4*)w + 4 * (size_t)i;
  i4 v0 = src[0], v1 = src[1], v2 = src[2], v3 = src[3];
  us8 lo, hi;
  lo[0] = f2bf((float)v0[0]); lo[1] = f2bf((float)v0[1]);
  lo[2] = f2bf((float)v0[2]); lo[3] = f2bf((float)v0[3]);
  lo[4] = f2bf((float)v1[0]); lo[5] = f2bf((float)v1[1]);
  lo[6] = f2bf((float)v1[2]); lo[7] = f2bf((float)v1[3]);
  hi[0] = f2bf((float)v2[0]); hi[1] = f2bf((float)v2[1]);
  hi[2] = f2bf((float)v2[2]); hi[3] = f2bf((float)v2[3]);
  hi[4] = f2bf((float)v3[0]); hi[5] = f2bf((float)v3[1]);
  hi[6] = f2bf((float)v3[2]); hi[7] = f2bf((float)v3[3]);
  wb[2 * (size_t)i] = lo;
  wb[2 * (size_t)i + 1] = hi;
}

// ------------- deep-pipelined GEMM, 128x64 wave-tiles via in-block K-split -------------
// 128x256 tile, BK=64, 8 waves = 4 N-strips (64 cols) x 2 K-halves (32 of each 64).
// Per wave per K-tile: Mrep=8 x Nrep=4 = 32 MFMA, 12 ds_read_b128 (22.9 B/KFLOP, m201 point).
// LDS buf (48KB x2): A[128][64]@0, Blo[128][64]@16K (B rows 0-127), Bhi@32K (rows 128-255).
// Phase A: read a[0..3]+b[0..3]; stage A,Bhi of t+1 -> buf d^1; barrier; 16 MFMA (m=0..3).
// Phase B: read a[4..7];        stage Blo of t+2  -> buf d;  vmcnt(2); barrier; 16 MFMA.
// Safety: no region is ds_read in the same phase that re-stages it (reads of a region
// always complete before the trailing barrier preceding its re-stage issue).
// vmcnt ledger: outstanding at phB wait = 2[t+1 Blo] + 4[t+1 A,Bhi] + 2[t+2 Blo] = 8;
// vmcnt(2) retires exactly tile t+1's 6 loads. Tail: vmcnt(0). One wait per K-tile.
// Epilogue: K-half pairs reduce through LDS (128KB), h=0 applies scale/bias + stores.

#define STAGE2(g0, g1, dst)          \
  do {                               \
    gload_lds16((g0), (dst));        \
    gload_lds16((g1), (dst) + 8192); \
  } while (0)

__global__ void __launch_bounds__(512, 2) gemm_pipe(
    const unsigned short* __restrict__ Xb,   // [M, K] bf16
    const unsigned short* __restrict__ Wb,   // [N, K] bf16
    const float* __restrict__ scale,         // [N]
    const float* __restrict__ bias,          // [N]
    float* __restrict__ out) {               // [M, N] fp32
  __shared__ __align__(16) char lds[131072];  // main loop uses [0,96K); epilogue all 128K

  const int tid = threadIdx.x;
  const int lane = tid & 63;
  const int wid = tid >> 6;   // 0..7
  const int s = wid & 3;      // N-strip (64 cols)
  const int h = wid >> 2;     // K-half (32 of each BK=64)
  const int fr = lane & 15;
  const int fq = lane >> 4;

  // T1: XCD-aware swizzle (688 % 8 == 0 -> bijective). Consecutive wg share bn.
  const int bid = blockIdx.x;
  const int wg = (bid & 7) * (GRID / 8) + (bid >> 3);
  const int bm = wg & 15;
  const int bn = wg >> 4;

  // staging source (inverse-swizzled): thread covers row=tid>>3 (+64), col16=(tid&7)^(row&7)
  const int srow = tid >> 3;
  const int scol = ((tid & 7) ^ (srow & 7)) * 8;  // elements
  const unsigned short* gA0 = Xb + (size_t)(bm * BM + srow) * K_DIM + scol;
  const unsigned short* gA1 = gA0 + (size_t)64 * K_DIM;
  const unsigned short* gB00 = Wb + (size_t)(bn * BN + srow) * K_DIM + scol;
  const unsigned short* gB01 = gB00 + (size_t)64 * K_DIM;
  const unsigned short* gB10 = Wb + (size_t)(bn * BN + 128 + srow) * K_DIM + scol;
  const unsigned short* gB11 = gB10 + (size_t)64 * K_DIM;

  // ds_read offsets (swizzled): byte col = (h*64 + fq*16) ^ ((row&7)<<4), row&7 == lane&7
  const int swz = (lane & 7) << 4;
  const int cb = ((h * 64) + (fq * 16)) ^ swz;
  const int boff = 16384 + ((s >> 1) * 16384);     // Blo or Bhi region
  const int brow = ((s & 1) * 64) * 128;           // + (j*16+fr)*128

  // ---- prologue: tile0 (A,Blo,Bhi -> buf0), tile1 Blo -> buf1
  {
    char* b0 = lds;
    STAGE2(gA0, gA1, b0 + 0 + wid * 1024);
    STAGE2(gB00, gB01, b0 + 16384 + wid * 1024);
    STAGE2(gB10, gB11, b0 + 32768 + wid * 1024);
    char* b1 = lds + 49152;
    STAGE2(gB00 + BK, gB01 + BK, b1 + 16384 + wid * 1024);
  }
  VMCNT2();   // tile0's 6 loads retired; tile1's Blo (2) stay in flight
  BARRIER();

  f32x4 acc[8][4] = {};

  for (int t = 0; t < NT; ++t) {
    const int d = t & 1;
    const char* buf = lds + d * 49152;
    const int koff = t * BK;

    // ---------- PHASE A ----------
    bf16x8 a0[4], b[4];
#pragma unroll
    for (int m = 0; m < 4; ++m)
      a0[m] = *(const bf16x8*)(buf + (m * 16 + fr) * 128 + cb);
#pragma unroll
    for (int j = 0; j < 4; ++j)
      b[j] = *(const bf16x8*)(buf + boff + brow + (j * 16 + fr) * 128 + cb);
    if (t + 1 < NT) {  // stage A, Bhi of tile t+1 -> buf d^1
      char* dst = lds + (d ^ 1) * 49152;
      STAGE2(gA0 + koff + BK, gA1 + koff + BK, dst + 0 + wid * 1024);
      STAGE2(gB10 + koff + BK, gB11 + koff + BK, dst + 32768 + wid * 1024);
    }
    BARRIER();
    __builtin_amdgcn_s_setprio(1);
#pragma unroll
    for (int m = 0; m < 4; ++m)
#pragma unroll
      for (int j = 0; j < 4; ++j)
        acc[m][j] = __builtin_amdgcn_mfma_f32_16x16x32_bf16(a0[m], b[j], acc[m][j], 0, 0, 0);
    __builtin_amdgcn_s_setprio(0);
    BARRIER();

    // ---------- PHASE B ----------
    bf16x8 a1[4];
#pragma unroll
    for (int m = 0; m < 4; ++m)
      a1[m] = *(const bf16x8*)(buf + ((m + 4) * 16 + fr) * 128 + cb);
    if (t + 2 < NT) {  // stage Blo of tile t+2 -> buf d
      char* dst = lds + d * 49152 + 16384 + wid * 1024;
      STAGE2(gB00 + koff + 2 * BK, gB01 + koff + 2 * BK, dst);
    }
    if (t + 2 < NT) { VMCNT2(); } else { VMCNT0(); }
    BARRIER();
    __builtin_amdgcn_s_setprio(1);
#pragma unroll
    for (int m = 0; m < 4; ++m)
#pragma unroll
      for (int j = 0; j < 4; ++j)
        acc[m + 4][j] = __builtin_amdgcn_mfma_f32_16x16x32_bf16(a1[m], b[j], acc[m + 4][j], 0, 0, 0);
    __builtin_amdgcn_s_setprio(0);
    BARRIER();
  }

  // ---- epilogue: reduce K-half pairs via LDS, then scale/bias + store (fp32)
  // C/D frag layout: col = j*16+fr, row = m*16 + fq*4 + jj (within wave's 128x64 tile)
  BARRIER();
  if (h == 1) {
    float* red = (float*)(lds + s * 32768);  // [128][64] f32 per strip
#pragma unroll
    for (int m = 0; m < 8; ++m)
#pragma unroll
      for (int j = 0; j < 4; ++j)
#pragma unroll
        for (int jj = 0; jj < 4; ++jj)
          red[(m * 16 + fq * 4 + jj) * 64 + (j * 16 + fr)] = acc[m][j][jj];
  }
  BARRIER();
  if (h == 0) {
    const float* red = (const float*)(lds + s * 32768);
#pragma unroll
    for (int j = 0; j < 4; ++j) {
      const int c = bn * BN + s * 64 + j * 16 + fr;
      const float sc = scale[c];
      const float bi = bias[c];
#pragma unroll
      for (int m = 0; m < 8; ++m) {
        const int r0 = bm * BM + m * 16 + fq * 4;
#pragma unroll
        for (int jj = 0; jj < 4; ++jj) {
          const float v = acc[m][j][jj] + red[(m * 16 + fq * 4 + jj) * 64 + (j * 16 + fr)];
          out[(size_t)(r0 + jj) * N_DIM + c] = v * sc + bi;
        }
      }
    }
  }
}

// ---------------- fallback (only if d_ws too small) ----------------

__global__ void __launch_bounds__(256) naive_kernel(
    const float* __restrict__ x, const int* __restrict__ w,
    const float* __restrict__ scale, const float* __restrict__ bias,
    float* __restrict__ out) {
  size_t idx = (size_t)blockIdx.x * 256 + threadIdx.x;
  if (idx >= (size_t)M_DIM * N_DIM) return;
  int m = (int)(idx / N_DIM);
  int n = (int)(idx % N_DIM);
  const float* xr = x + (size_t)m * K_DIM;
  const int* wr = w + (size_t)n * K_DIM;
  float acc = 0.f;
  for (int k = 0; k < K_DIM; k += 4) {
    f4 xv = *(const f4*)(xr + k);
    i4 wv = *(const i4*)(wr + k);
    acc += xv[0] * (float)wv[0];
    acc += xv[1] * (float)wv[1];
    acc += xv[2] * (float)wv[2];
    acc += xv[3] * (float)wv[3];
  }
  out[idx] = acc * scale[n] + bias[n];
}

// ---------------- launch ----------------

extern "C" void kernel_launch(void* const* d_in, const int* in_sizes, int n_in,
                              void* d_out, int out_size, void* d_ws, size_t ws_size,
                              hipStream_t stream) {
  const float* x = (const float*)d_in[0];
  const int* wq = (const int*)d_in[1];
  const float* scale = (const float*)d_in[2];
  const float* bias = (const float*)d_in[3];
  float* out = (float*)d_out;

  const size_t xb_bytes = (size_t)M_DIM * K_DIM * 2;   // 16.8 MB
  const size_t wb_bytes = (size_t)N_DIM * K_DIM * 2;   // 90.2 MB

  if (ws_size >= xb_bytes + wb_bytes) {
    unsigned short* xb = (unsigned short*)d_ws;
    unsigned short* wb = (unsigned short*)((char*)d_ws + xb_bytes);

    const int n8 = M_DIM * K_DIM / 8;
    cvt_x_kernel<<<(n8 + 255) / 256, 256, 0, stream>>>(x, (us8*)xb, n8);

    const int n16 = N_DIM * K_DIM / 16;
    cvt_w_kernel<<<(n16 + 255) / 256, 256, 0, stream>>>(wq, (us8*)wb, n16);

    gemm_pipe<<<GRID, 512, 0, stream>>>(xb, wb, scale, bias, out);
  } else {
    const size_t total = (size_t)M_DIM * N_DIM;
    naive_kernel<<<(unsigned)((total + 255) / 256), 256, 0, stream>>>(x, wq, scale, bias, out);
  }
}

// Round 5
// 266.392 us; speedup vs baseline: 1.0665x; 1.0665x over previous
//
#include <hip/hip_runtime.h>
#include <stdint.h>
#include <stddef.h>

#define M_DIM 2048
#define N_DIM 11008
#define K_DIM 4096
#define BM 128
#define BN 256
#define BK 64
#define NT (K_DIM / BK)   // 64
#define NBM (M_DIM / BM)  // 16
#define NBN (N_DIM / BN)  // 43
#define GRID (NBM * NBN)  // 688 (divisible by 8 -> XCD swizzle bijective)

typedef __attribute__((ext_vector_type(4))) float f32x4;
typedef __attribute__((ext_vector_type(4))) float f4;
typedef __attribute__((ext_vector_type(4))) int i4;
typedef __attribute__((ext_vector_type(8))) __bf16 bf16x8;
typedef __attribute__((ext_vector_type(8))) unsigned short us8;

#define VMCNT6() asm volatile("s_waitcnt vmcnt(6)" ::: "memory")
#define VMCNT0() asm volatile("s_waitcnt vmcnt(0)" ::: "memory")
#define FENCE() asm volatile("" ::: "memory")
#define BARRIER()                 \
  do {                            \
    FENCE();                      \
    __builtin_amdgcn_s_barrier(); \
    FENCE();                      \
  } while (0)

// round-to-nearest-even fp32 -> bf16
__device__ inline unsigned short f2bf(float f) {
  unsigned u = __builtin_bit_cast(unsigned, f);
  u += 0x7fffu + ((u >> 16) & 1u);
  return (unsigned short)(u >> 16);
}

__device__ inline void gload_lds16(const void* g, void* l) {
  __builtin_amdgcn_global_load_lds((const __attribute__((address_space(1))) void*)g,
                                   (__attribute__((address_space(3))) void*)l, 16, 0, 0);
}

// ---------------- conversion kernels ----------------

__global__ void __launch_bounds__(256) cvt_x_kernel(const float* __restrict__ x,
                                                    us8* __restrict__ xb, int n8) {
  int i = blockIdx.x * 256 + threadIdx.x;
  if (i >= n8) return;
  const f4* src = (const f4*)x;
  f4 a = src[2 * i];
  f4 b = src[2 * i + 1];
  us8 o;
  o[0] = f2bf(a[0]); o[1] = f2bf(a[1]); o[2] = f2bf(a[2]); o[3] = f2bf(a[3]);
  o[4] = f2bf(b[0]); o[5] = f2bf(b[1]); o[6] = f2bf(b[2]); o[7] = f2bf(b[3]);
  xb[i] = o;
}

// W_q arrives as int32 per element; int8-range values are exact in bf16.
__global__ void __launch_bounds__(256) cvt_w_kernel(const int* __restrict__ w,
                                                    us8* __restrict__ wb, int n16) {
  int i = blockIdx.x * 256 + threadIdx.x;
  if (i >= n16) return;
  const i4* src = (const i4*)w + 4 * (size_t)i;
  i4 v0 = src[0], v1 = src[1], v2 = src[2], v3 = src[3];
  us8 lo, hi;
  lo[0] = f2bf((float)v0[0]); lo[1] = f2bf((float)v0[1]);
  lo[2] = f2bf((float)v0[2]); lo[3] = f2bf((float)v0[3]);
  lo[4] = f2bf((float)v1[0]); lo[5] = f2bf((float)v1[1]);
  lo[6] = f2bf((float)v1[2]); lo[7] = f2bf((float)v1[3]);
  hi[0] = f2bf((float)v2[0]); hi[1] = f2bf((float)v2[1]);
  hi[2] = f2bf((float)v2[2]); hi[3] = f2bf((float)v2[3]);
  hi[4] = f2bf((float)v3[0]); hi[5] = f2bf((float)v3[1]);
  hi[6] = f2bf((float)v3[2]); hi[7] = f2bf((float)v3[3]);
  wb[2 * (size_t)i] = lo;
  wb[2 * (size_t)i + 1] = hi;
}

// ------------- 3-buffer deep-pipelined GEMM, 128x64 wave-tiles -------------
// 128x256 tile, BK=64, 8 waves = 4 N-strips (64 cols) x 2 K-halves (32 of each 64).
// LDS: 3 bufs x 48KB {A[128][64]@0, Blo@16K, Bhi@32K}; epilogue reuses [0,128K).
// phA(t): ds_read a0(rows 0-63) + b (this wave's B strip, held in regs across phases);
//         stage FULL tile t+2 (6 gloads) -> buf (t+2)%3; barrier; 16 MFMA; barrier.
// phB(t): ds_read a1(rows 64-127); vmcnt(6) [retires tile t+1's 6 loads, issued
//         phA(t-1) = 3 phases earlier]; barrier; 16 MFMA; barrier.
// Ledger (sim'd): steady outstanding at wait = S6(t+1) 6 + S6(t+2) 6 = 12 -> vmcnt(6)
// retires exactly S6(t+1). Tail: t=NT-2 -> vmcnt(0); t=NT-1 -> no wait.
// Region safety: staged buffer served tile t-1; its last readers (phB(t-1) a1) retire
// before phB(t-1)'s MFMA (lgkmcnt), which precedes the trailing barrier before phA(t).
// Epilogue: K-half pairs reduce through LDS with fq-XOR swizzle (2-way = free).

#define STAGE2(g0, g1, dst)          \
  do {                               \
    gload_lds16((g0), (dst));        \
    gload_lds16((g1), (dst) + 8192); \
  } while (0)

#define STAGE6(base, ko)                                            \
  do {                                                              \
    STAGE2(gA0 + (ko), gA1 + (ko), (base) + 0 + wid * 1024);        \
    STAGE2(gB00 + (ko), gB01 + (ko), (base) + 16384 + wid * 1024);  \
    STAGE2(gB10 + (ko), gB11 + (ko), (base) + 32768 + wid * 1024);  \
  } while (0)

__global__ void __launch_bounds__(512, 2) gemm_pipe(
    const unsigned short* __restrict__ Xb,   // [M, K] bf16
    const unsigned short* __restrict__ Wb,   // [N, K] bf16
    const float* __restrict__ scale,         // [N]
    const float* __restrict__ bias,          // [N]
    float* __restrict__ out) {               // [M, N] fp32
  __shared__ __align__(16) char lds[147456];  // 3 x 48KB

  const int tid = threadIdx.x;
  const int lane = tid & 63;
  const int wid = tid >> 6;   // 0..7
  const int s = wid & 3;      // N-strip (64 cols)
  const int h = wid >> 2;     // K-half (32 of each BK=64)
  const int fr = lane & 15;
  const int fq = lane >> 4;

  // T1: XCD-aware swizzle (688 % 8 == 0 -> bijective). Consecutive wg share bn.
  const int bid = blockIdx.x;
  const int wg = (bid & 7) * (GRID / 8) + (bid >> 3);
  const int bm = wg & 15;
  const int bn = wg >> 4;

  // staging source (inverse-swizzled): thread covers row=tid>>3 (+64), col16=(tid&7)^(row&7)
  const int srow = tid >> 3;
  const int scol = ((tid & 7) ^ (srow & 7)) * 8;  // elements
  const unsigned short* gA0 = Xb + (size_t)(bm * BM + srow) * K_DIM + scol;
  const unsigned short* gA1 = gA0 + (size_t)64 * K_DIM;
  const unsigned short* gB00 = Wb + (size_t)(bn * BN + srow) * K_DIM + scol;
  const unsigned short* gB01 = gB00 + (size_t)64 * K_DIM;
  const unsigned short* gB10 = Wb + (size_t)(bn * BN + 128 + srow) * K_DIM + scol;
  const unsigned short* gB11 = gB10 + (size_t)64 * K_DIM;

  // ds_read offsets (swizzled): byte col = (h*64 + fq*16) ^ ((row&7)<<4), row&7 == lane&7
  const int swz = (lane & 7) << 4;
  const int cb = ((h * 64) + (fq * 16)) ^ swz;
  const int boff = 16384 + ((s >> 1) * 16384);     // Blo or Bhi region
  const int brow = ((s & 1) * 64) * 128;           // + (j*16+fr)*128

  char* const buf0 = lds;
  char* const buf1 = lds + 49152;
  char* const buf2 = lds + 98304;

  // ---- prologue: stage tiles 0 and 1 fully; retire tile 0; keep tile 1 in flight
  STAGE6(buf0, 0);
  STAGE6(buf1, BK);
  VMCNT6();
  BARRIER();

  f32x4 acc[8][4] = {};
  char* bc = buf0;    // tile t
  char* bnx = buf1;   // tile t+1
  char* bnn = buf2;   // tile t+2 (staging target)

  for (int t = 0; t < NT; ++t) {
    const int koff = t * BK;

    // ---------- PHASE A ----------
    bf16x8 a0[4], b[4];
#pragma unroll
    for (int m = 0; m < 4; ++m)
      a0[m] = *(const bf16x8*)(bc + (m * 16 + fr) * 128 + cb);
#pragma unroll
    for (int j = 0; j < 4; ++j)
      b[j] = *(const bf16x8*)(bc + boff + brow + (j * 16 + fr) * 128 + cb);
    if (t + 2 < NT) STAGE6(bnn, koff + 2 * BK);
    BARRIER();
    __builtin_amdgcn_s_setprio(1);
#pragma unroll
    for (int m = 0; m < 4; ++m)
#pragma unroll
      for (int j = 0; j < 4; ++j)
        acc[m][j] = __builtin_amdgcn_mfma_f32_16x16x32_bf16(a0[m], b[j], acc[m][j], 0, 0, 0);
    __builtin_amdgcn_s_setprio(0);
    BARRIER();

    // ---------- PHASE B ----------
    bf16x8 a1[4];
#pragma unroll
    for (int m = 0; m < 4; ++m)
      a1[m] = *(const bf16x8*)(bc + 8192 + (m * 16 + fr) * 128 + cb);
    if (t + 2 < NT) { VMCNT6(); } else if (t + 1 < NT) { VMCNT0(); }
    BARRIER();
    __builtin_amdgcn_s_setprio(1);
#pragma unroll
    for (int m = 0; m < 4; ++m)
#pragma unroll
      for (int j = 0; j < 4; ++j)
        acc[m + 4][j] = __builtin_amdgcn_mfma_f32_16x16x32_bf16(a1[m], b[j], acc[m + 4][j], 0, 0, 0);
    __builtin_amdgcn_s_setprio(0);
    BARRIER();

    // rotate buffers
    char* tmp = bc; bc = bnx; bnx = bnn; bnn = tmp;
  }

  // ---- epilogue: reduce K-half pairs via LDS (fq-XOR swizzle -> 2-way, free),
  // then scale/bias + store. C/D frag: col=j*16+fr, row=m*16+fq*4+jj.
  BARRIER();
  if (h == 1) {
    float* red = (float*)(lds + s * 32768);  // [128][64] f32 per strip
#pragma unroll
    for (int m = 0; m < 8; ++m)
#pragma unroll
      for (int j = 0; j < 4; ++j)
#pragma unroll
        for (int jj = 0; jj < 4; ++jj)
          red[(m * 16 + fq * 4 + jj) * 64 + ((j * 16 + fr) ^ (fq << 4))] = acc[m][j][jj];
  }
  BARRIER();
  if (h == 0) {
    const float* red = (const float*)(lds + s * 32768);
#pragma unroll
    for (int j = 0; j < 4; ++j) {
      const int c = bn * BN + s * 64 + j * 16 + fr;
      const float sc = scale[c];
      const float bi = bias[c];
#pragma unroll
      for (int m = 0; m < 8; ++m) {
        const int r0 = bm * BM + m * 16 + fq * 4;
#pragma unroll
        for (int jj = 0; jj < 4; ++jj) {
          const float v = acc[m][j][jj] +
                          red[(m * 16 + fq * 4 + jj) * 64 + ((j * 16 + fr) ^ (fq << 4))];
          out[(size_t)(r0 + jj) * N_DIM + c] = v * sc + bi;
        }
      }
    }
  }
}

// ---------------- fallback (only if d_ws too small) ----------------

__global__ void __launch_bounds__(256) naive_kernel(
    const float* __restrict__ x, const int* __restrict__ w,
    const float* __restrict__ scale, const float* __restrict__ bias,
    float* __restrict__ out) {
  size_t idx = (size_t)blockIdx.x * 256 + threadIdx.x;
  if (idx >= (size_t)M_DIM * N_DIM) return;
  int m = (int)(idx / N_DIM);
  int n = (int)(idx % N_DIM);
  const float* xr = x + (size_t)m * K_DIM;
  const int* wr = w + (size_t)n * K_DIM;
  float acc = 0.f;
  for (int k = 0; k < K_DIM; k += 4) {
    f4 xv = *(const f4*)(xr + k);
    i4 wv = *(const i4*)(wr + k);
    acc += xv[0] * (float)wv[0];
    acc += xv[1] * (float)wv[1];
    acc += xv[2] * (float)wv[2];
    acc += xv[3] * (float)wv[3];
  }
  out[idx] = acc * scale[n] + bias[n];
}

// ---------------- launch ----------------

extern "C" void kernel_launch(void* const* d_in, const int* in_sizes, int n_in,
                              void* d_out, int out_size, void* d_ws, size_t ws_size,
                              hipStream_t stream) {
  const float* x = (const float*)d_in[0];
  const int* wq = (const int*)d_in[1];
  const float* scale = (const float*)d_in[2];
  const float* bias = (const float*)d_in[3];
  float* out = (float*)d_out;

  const size_t xb_bytes = (size_t)M_DIM * K_DIM * 2;   // 16.8 MB
  const size_t wb_bytes = (size_t)N_DIM * K_DIM * 2;   // 90.2 MB

  if (ws_size >= xb_bytes + wb_bytes) {
    unsigned short* xb = (unsigned short*)d_ws;
    unsigned short* wb = (unsigned short*)((char*)d_ws + xb_bytes);

    const int n8 = M_DIM * K_DIM / 8;
    cvt_x_kernel<<<(n8 + 255) / 256, 256, 0, stream>>>(x, (us8*)xb, n8);

    const int n16 = N_DIM * K_DIM / 16;
    cvt_w_kernel<<<(n16 + 255) / 256, 256, 0, stream>>>(wq, (us8*)wb, n16);

    gemm_pipe<<<GRID, 512, 0, stream>>>(xb, wb, scale, bias, out);
  } else {
    const size_t total = (size_t)M_DIM * N_DIM;
    naive_kernel<<<(unsigned)((total + 255) / 256), 256, 0, stream>>>(x, wq, scale, bias, out);
  }
}